// Round 3
// baseline (366.193 us; speedup 1.0000x reference)
//
#include <hip/hip_runtime.h>

#define Bz 64
#define Nn 577
#define Cc 768
#define Hh 12
#define Dd 64
#define SCALE 0.125f
#define YSEG 8

typedef __attribute__((ext_vector_type(8))) short short8;
typedef __attribute__((ext_vector_type(4))) float float4v;

__device__ __forceinline__ unsigned short bf16rne(float f) {
  unsigned u = __float_as_uint(f);
  u += 0x7FFFu + ((u >> 16) & 1u);
  return (unsigned short)(u >> 16);
}

__device__ __forceinline__ short8 cvt8(float4 a, float4 b) {
  short8 v;
  v[0] = (short)bf16rne(a.x); v[1] = (short)bf16rne(a.y);
  v[2] = (short)bf16rne(a.z); v[3] = (short)bf16rne(a.w);
  v[4] = (short)bf16rne(b.x); v[5] = (short)bf16rne(b.y);
  v[6] = (short)bf16rne(b.z); v[7] = (short)bf16rne(b.w);
  return v;
}

__device__ __forceinline__ short8 cvt8v(float4v a, float4v b) {
  short8 v;
  v[0] = (short)bf16rne(a[0]); v[1] = (short)bf16rne(a[1]);
  v[2] = (short)bf16rne(a[2]); v[3] = (short)bf16rne(a[3]);
  v[4] = (short)bf16rne(b[0]); v[5] = (short)bf16rne(b[1]);
  v[6] = (short)bf16rne(b[2]); v[7] = (short)bf16rne(b[3]);
  return v;
}

// ws layout (float units), Tier A (needs ~81.1 MB):
//   rb     @ 0        : 786,432 bf16 (393,216 float slots) [B][24 s][4 q][16 m=h][8 j]
//   qf     @ 393216   : [B][C] fp32
//   logits @ 442368   : [B][H][N] fp32
//   attnT  @ 885504   : [B][N][H] fp32
//   ypart  @ 1328640  : [B][YSEG][H][C] fp32 (plain stores, summed in gemm<1>)
//   cls    @ 6047232  : [B][C] fp32
//   xbf    @ 6096384  : [B][N][C] bf16 = 28,360,704 shorts = 14,180,352 slots
// Tier C (old, needs 7.87 MB): y @ 1328640 (atomic), cls @ 1918464.

// ============ k_gemm64: C(64 x 768) = A(64 x 768) @ W_rows^T + bias ===========
// MODE 0: q   = X0 @ Wq^T      (A row stride Nn*Cc;  W rows j;        out q)
// MODE 1: cls = Y_h @ Wv^T     (A = ypart[b][seg][h=jt>>2]; SEGS summed; W rows 2C+j)
// MODE 2: out0 = cls @ projW^T (A row stride Cc;     W rows j;        out row0)
template <int MODE, int SEGS>
__global__ __launch_bounds__(256) void k_gemm64(const float* __restrict__ A,
                                                const float* __restrict__ W,
                                                const float* __restrict__ bias,
                                                float* __restrict__ out) {
  int tile = blockIdx.x;            // 0..191
  int jt = tile % 48, bt = tile / 48;
  int wave = threadIdx.x >> 6, lane = threadIdx.x & 63;
  int m = lane & 15, quad = lane >> 4;
  int brow = bt * 16 + m;
  int jrow = jt * 16 + m;
  size_t aoff;
  if (MODE == 0)      aoff = (size_t)brow * (Nn * Cc);
  else if (MODE == 1) aoff = (size_t)brow * (SEGS * Hh * Cc) + (size_t)(jt >> 2) * Cc;
  else                aoff = (size_t)brow * Cc;
  size_t woff = (MODE == 1) ? (size_t)(2 * Cc + jrow) * Cc : (size_t)jrow * Cc;
  const float4v* Ap = (const float4v*)(A + aoff) + wave * 48 + quad * 2;
  const float4v* Wp = (const float4v*)(W + woff) + wave * 48 + quad * 2;
  float4v acc = {0.f, 0.f, 0.f, 0.f};
#pragma unroll
  for (int s = 0; s < 6; ++s) {
    float4v a0, a1;
    if (MODE == 1 && SEGS > 1) {
      a0 = (float4v){0.f, 0.f, 0.f, 0.f};
      a1 = a0;
#pragma unroll
      for (int seg = 0; seg < SEGS; ++seg) {
        a0 += Ap[seg * 2304 + s * 8];      // 2304 = H*C/4 float4 per seg
        a1 += Ap[seg * 2304 + s * 8 + 1];
      }
    } else {
      a0 = Ap[s * 8]; a1 = Ap[s * 8 + 1];
    }
    float4v w0 = Wp[s * 8], w1 = Wp[s * 8 + 1];
    acc = __builtin_amdgcn_mfma_f32_16x16x32_bf16(cvt8v(a0, a1), cvt8v(w0, w1),
                                                  acc, 0, 0, 0);
  }
  __shared__ float red[4][64][4];
#pragma unroll
  for (int reg = 0; reg < 4; ++reg) red[wave][lane][reg] = acc[reg];
  __syncthreads();
  if (wave == 0) {
#pragma unroll
    for (int reg = 0; reg < 4; ++reg) {
      float v = red[0][lane][reg] + red[1][lane][reg] +
                red[2][lane][reg] + red[3][lane][reg];
      int j = jt * 16 + m;
      int bb = bt * 16 + quad * 4 + reg;
      float bv = (MODE == 1) ? bias[2 * Cc + j] : bias[j];
      if (MODE == 2) out[(size_t)bb * (Nn * Cc) + j] = v + bv;
      else           out[(size_t)bb * Cc + j] = v + bv;
    }
  }
}

// ====== k_r: rb[b][s][q][h][j] = bf16(SCALE * sum_d q[b,h,d] * Wk[h,d,c]) =====
__global__ __launch_bounds__(256) void k_r(const float* __restrict__ qf,
                                           const float* __restrict__ qkv_w,
                                           unsigned short* __restrict__ rb) {
  int h = blockIdx.x % Hh, bg = blockIdx.x / Hh;
  int t = threadIdx.x;
  __shared__ float qs2[Dd][8];
  for (int idx = t; idx < 512; idx += 256) {
    int bb = idx >> 6, d = idx & 63;
    qs2[d][bb] = qf[(size_t)(bg * 8 + bb) * Cc + h * Dd + d];
  }
  __syncthreads();
  float acc[8][3];
#pragma unroll
  for (int bb = 0; bb < 8; ++bb)
#pragma unroll
    for (int i = 0; i < 3; ++i) acc[bb][i] = 0.f;
  const float* wk = qkv_w + (size_t)(Cc + h * Dd) * Cc;
  for (int d = 0; d < Dd; ++d) {
    float w0 = wk[(size_t)d * Cc + t];
    float w1 = wk[(size_t)d * Cc + t + 256];
    float w2 = wk[(size_t)d * Cc + t + 512];
    float4 qa = *(const float4*)&qs2[d][0];
    float4 qb = *(const float4*)&qs2[d][4];
    float qv[8] = {qa.x, qa.y, qa.z, qa.w, qb.x, qb.y, qb.z, qb.w};
#pragma unroll
    for (int bb = 0; bb < 8; ++bb) {
      acc[bb][0] += qv[bb] * w0;
      acc[bb][1] += qv[bb] * w1;
      acc[bb][2] += qv[bb] * w2;
    }
  }
#pragma unroll
  for (int bb = 0; bb < 8; ++bb) {
    size_t base = (size_t)(bg * 8 + bb) * 12288 + h * 8;
#pragma unroll
    for (int i = 0; i < 3; ++i) {
      int c = t + i * 256;
      int s = c >> 5, qq = (c >> 3) & 3, j = c & 7;
      rb[base + s * 512 + qq * 128 + j] = bf16rne(acc[bb][i] * SCALE);
    }
  }
}

// ===== k_prep: out[:,1:,:] = x[:,1:,:]  AND  xbf = bf16(x)  (one x stream) ====
// 6924 blocks x 256 threads = 1,772,544 threads, 16 floats each: exact cover of
// 64*577*768 = 28,360,704 floats.
__global__ __launch_bounds__(256) void k_prep(const float* __restrict__ x,
                                              float* __restrict__ out,
                                              unsigned short* __restrict__ xbf) {
  int i = blockIdx.x * 256 + threadIdx.x;       // 0 .. 1,772,543
  const float4v* xi = (const float4v*)x + (size_t)i * 4;
  float4v a0 = xi[0], a1 = xi[1], a2 = xi[2], a3 = xi[3];
  short8* xb = (short8*)xbf + (size_t)i * 2;
  xb[0] = cvt8v(a0, a1);
  xb[1] = cvt8v(a2, a3);
  int r = i % (Nn * 48);                        // 48 groups of 16 per row
  if (r >= 48) {                                // n >= 1
    float4v* oo = (float4v*)out + (size_t)i * 4;
    __builtin_nontemporal_store(a0, oo);
    __builtin_nontemporal_store(a1, oo + 1);
    __builtin_nontemporal_store(a2, oo + 2);
    __builtin_nontemporal_store(a3, oo + 3);
  }
}

// ===== k_logits: MFMA straight from global (no LDS, no barriers) ==============
// XBF=1: B-operand loaded pre-converted bf16 (1 x 16B load); XBF=0: fp32 + cvt.
template <int XBF>
__global__ __launch_bounds__(256) void k_logits(const float* __restrict__ x,
                                                const unsigned short* __restrict__ xbf,
                                                const unsigned short* __restrict__ rb,
                                                float* __restrict__ logits) {
  int b = blockIdx.x / 10, tile = blockIdx.x % 10;
  int wave = threadIdx.x >> 6, lane = threadIdx.x & 63;
  int m = lane & 15, quad = lane >> 4;
  int n = tile * 64 + wave * 16 + m;
  int nc = n > 576 ? 576 : n;
  const short8* ag = (const short8*)(rb + (size_t)b * 12288);
  const short8* xg8 = (const short8*)(xbf + (size_t)b * Nn * Cc) + (size_t)nc * 96 + quad;
  const float4* xg = (const float4*)(x + (size_t)b * Nn * Cc) + (size_t)nc * 192 + quad * 2;
  float4v acc = {0.f, 0.f, 0.f, 0.f};
#pragma unroll 8
  for (int s = 0; s < 24; ++s) {
    short8 a = ag[s * 64 + quad * 16 + m];
    short8 bfrag;
    if (XBF) {
      bfrag = xg8[s * 4];
    } else {
      float4 f0 = xg[s * 8], f1 = xg[s * 8 + 1];
      bfrag = cvt8(f0, f1);
    }
    acc = __builtin_amdgcn_mfma_f32_16x16x32_bf16(a, bfrag, acc, 0, 0, 0);
  }
  if (n < Nn) {
#pragma unroll
    for (int reg = 0; reg < 4; ++reg) {
      int hh = quad * 4 + reg;
      if (hh < Hh) logits[((size_t)b * Hh + hh) * Nn + n] = acc[reg];
    }
  }
}

// ---------------- softmax over n, write transposed attnT[b][n][h] -------------
__global__ __launch_bounds__(64) void k_softmax(const float* __restrict__ logits,
                                                float* __restrict__ attnT) {
  int bh = blockIdx.x;
  int b = bh / Hh, h = bh % Hh;
  const float* row = logits + (size_t)bh * Nn;
  int t = threadIdx.x;
  float vals[10];
  float m = -1e30f;
#pragma unroll
  for (int i = 0; i < 10; ++i) {
    int n = i * 64 + t;
    vals[i] = (n < Nn) ? row[n] : -1e30f;
    m = fmaxf(m, vals[i]);
  }
#pragma unroll
  for (int off = 32; off; off >>= 1) m = fmaxf(m, __shfl_down(m, off));
  m = __shfl(m, 0);
  float s = 0.f;
#pragma unroll
  for (int i = 0; i < 10; ++i) { vals[i] = __expf(vals[i] - m); s += vals[i]; }
#pragma unroll
  for (int off = 32; off; off >>= 1) s += __shfl_down(s, off);
  float inv = 1.f / __shfl(s, 0);
#pragma unroll
  for (int i = 0; i < 10; ++i) {
    int n = i * 64 + t;
    if (n < Nn) attnT[((size_t)b * Nn + n) * Hh + h] = vals[i] * inv;
  }
}

// ===== k_y3: ypart[b,seg,h,c] = sum_{n in 1/3 of seg} attn * x ================
// 512 blocks x 576 threads (9 waves). 3-way intra-block n-split, LDS reduce,
// plain stores (no atomics).
__global__ __launch_bounds__(576) void k_y3(const float* __restrict__ x,
                                            const float* __restrict__ attnT,
                                            float* __restrict__ ypart) {
  int b = blockIdx.x / YSEG, seg = blockIdx.x % YSEG;
  int c4 = threadIdx.x % 192;
  int sub = threadIdx.x / 192;              // 0..2, wave-uniform (192 = 3 waves)
  int n0 = seg * Nn / YSEG, n1 = (seg + 1) * Nn / YSEG;
  int len = n1 - n0;
  int a0 = n0 + sub * len / 3, a1 = n0 + (sub + 1) * len / 3;
  float4v acc[Hh];
#pragma unroll
  for (int h = 0; h < Hh; ++h) acc[h] = (float4v){0.f, 0.f, 0.f, 0.f};
  const float4v* x4 = (const float4v*)(x + (size_t)b * Nn * Cc);
  const float* at = attnT + (size_t)b * Nn * Hh;
#pragma unroll 4
  for (int n = a0; n < a1; ++n) {
    float4v xv = x4[(size_t)n * 192 + c4];
#pragma unroll
    for (int h = 0; h < Hh; ++h) acc[h] += at[n * Hh + h] * xv;  // at: s_load
  }
  __shared__ float4v red[192][Hh];          // 36,864 B
  if (sub == 2) {
#pragma unroll
    for (int h = 0; h < Hh; ++h) red[c4][h] = acc[h];
  }
  __syncthreads();
  if (sub == 1) {
#pragma unroll
    for (int h = 0; h < Hh; ++h) { acc[h] += red[c4][h]; red[c4][h] = acc[h]; }
  }
  __syncthreads();
  if (sub == 0) {
    float4v* yp = (float4v*)(ypart + ((size_t)(b * YSEG + seg)) * (Hh * Cc));
#pragma unroll
    for (int h = 0; h < Hh; ++h) yp[h * 192 + c4] = acc[h] + red[c4][h];
  }
}

// ----------------- Tier C fallback kernels (previous verified path) -----------
__global__ __launch_bounds__(256) void k_zero(float* __restrict__ y) {
  ((float4*)y)[blockIdx.x * 256 + threadIdx.x] = make_float4(0.f, 0.f, 0.f, 0.f);
}

__global__ __launch_bounds__(192) void k_y_atomic(const float* __restrict__ x,
                                                  const float* __restrict__ attnT,
                                                  float* __restrict__ y) {
  int b = blockIdx.x / YSEG, seg = blockIdx.x % YSEG;
  int n0 = seg * Nn / YSEG, n1 = (seg + 1) * Nn / YSEG;
  int c4 = threadIdx.x;
  float4 acc[Hh];
#pragma unroll
  for (int h = 0; h < Hh; ++h) acc[h] = make_float4(0.f, 0.f, 0.f, 0.f);
  const float4* x4 = (const float4*)(x + (size_t)b * Nn * Cc);
  const float* at = attnT + (size_t)b * Nn * Hh;
#pragma unroll 8
  for (int n = n0; n < n1; ++n) {
    float4 xv = x4[(size_t)n * 192 + c4];
#pragma unroll
    for (int h = 0; h < Hh; ++h) {
      float a = at[n * Hh + h];
      acc[h].x += a * xv.x; acc[h].y += a * xv.y;
      acc[h].z += a * xv.z; acc[h].w += a * xv.w;
    }
  }
  float* yb = y + (size_t)b * Hh * Cc;
#pragma unroll
  for (int h = 0; h < Hh; ++h) {
    float* p = yb + h * Cc + c4 * 4;
    atomicAdd(p + 0, acc[h].x); atomicAdd(p + 1, acc[h].y);
    atomicAdd(p + 2, acc[h].z); atomicAdd(p + 3, acc[h].w);
  }
}

__global__ __launch_bounds__(256) void k_copy(const float* __restrict__ x,
                                              float* __restrict__ out) {
  int idx = blockIdx.x * 256 + threadIdx.x;
  const float4* xi = (const float4*)x;
  float4* oo = (float4*)out;
  for (int i = idx; i < 7077888; i += 262144) {
    int b = i / 110592;
    int r = i - b * 110592;
    size_t off = (size_t)b * 110784 + 192 + r;
    oo[off] = xi[off];
  }
}

extern "C" void kernel_launch(void* const* d_in, const int* in_sizes, int n_in,
                              void* d_out, int out_size, void* d_ws, size_t ws_size,
                              hipStream_t stream) {
  const float* x      = (const float*)d_in[0];
  const float* qkv_w  = (const float*)d_in[1];
  const float* qkv_b  = (const float*)d_in[2];
  const float* proj_w = (const float*)d_in[3];
  const float* proj_b = (const float*)d_in[4];
  float* out = (float*)d_out;
  float* ws = (float*)d_ws;

  unsigned short* rb = (unsigned short*)ws;     // 786,432 bf16
  float* qf     = ws + 393216;
  float* logits = ws + 442368;
  float* attnT  = ws + 885504;
  float* ypart  = ws + 1328640;                 // 4,718,592 floats
  float* cls    = ws + 6047232;                 // 49,152 floats
  unsigned short* xbf = (unsigned short*)(ws + 6096384);  // 28,360,704 shorts

  const size_t NEED_XBF  = (size_t)(6096384 + 14180352) * 4;  // 81,106,944 B
  const size_t NEED_PART = (size_t)6096384 * 4;               // ~24.4 MB

  if (ws_size >= NEED_XBF) {
    // Tier A: prep (copy + bf16), bf16 logits, partial-buffer y.
    k_prep<<<6924, 256, 0, stream>>>(x, out, xbf);
    k_gemm64<0, 1><<<192, 256, 0, stream>>>(x, qkv_w, qkv_b, qf);
    k_r<<<96, 256, 0, stream>>>(qf, qkv_w, rb);
    k_logits<1><<<Bz * 10, 256, 0, stream>>>(x, xbf, rb, logits);
    k_softmax<<<Bz * Hh, 64, 0, stream>>>(logits, attnT);
    k_y3<<<Bz * YSEG, 576, 0, stream>>>(x, attnT, ypart);
    k_gemm64<1, YSEG><<<192, 256, 0, stream>>>(ypart, qkv_w, qkv_b, cls);
    k_gemm64<2, 1><<<192, 256, 0, stream>>>(cls, proj_w, proj_b, out);
  } else if (ws_size >= NEED_PART) {
    // Tier B: no xbf; fp32 logits; partial-buffer y; separate copy.
    k_gemm64<0, 1><<<192, 256, 0, stream>>>(x, qkv_w, qkv_b, qf);
    k_r<<<96, 256, 0, stream>>>(qf, qkv_w, rb);
    k_logits<0><<<Bz * 10, 256, 0, stream>>>(x, (const unsigned short*)x, rb, logits);
    k_softmax<<<Bz * Hh, 64, 0, stream>>>(logits, attnT);
    k_y3<<<Bz * YSEG, 576, 0, stream>>>(x, attnT, ypart);
    k_gemm64<1, YSEG><<<192, 256, 0, stream>>>(ypart, qkv_w, qkv_b, cls);
    k_gemm64<2, 1><<<192, 256, 0, stream>>>(cls, proj_w, proj_b, out);
    k_copy<<<1024, 256, 0, stream>>>(x, out);
  } else {
    // Tier C: previous verified pipeline (7.87 MB ws).
    float* y     = ws + 1328640;
    float* cls_c = ws + 1918464;
    k_zero<<<576, 256, 0, stream>>>(y);
    k_gemm64<0, 1><<<192, 256, 0, stream>>>(x, qkv_w, qkv_b, qf);
    k_r<<<96, 256, 0, stream>>>(qf, qkv_w, rb);
    k_logits<0><<<Bz * 10, 256, 0, stream>>>(x, (const unsigned short*)x, rb, logits);
    k_softmax<<<Bz * Hh, 64, 0, stream>>>(logits, attnT);
    k_y_atomic<<<Bz * YSEG, 192, 0, stream>>>(x, attnT, y);
    k_gemm64<1, 1><<<192, 256, 0, stream>>>(y, qkv_w, qkv_b, cls_c);
    k_gemm64<2, 1><<<192, 256, 0, stream>>>(cls_c, proj_w, proj_b, out);
  }
}

// Round 4
// 316.136 us; speedup vs baseline: 1.1583x; 1.1583x over previous
//
#include <hip/hip_runtime.h>

#define Bz 64
#define Nn 577
#define Cc 768
#define Hh 12
#define Dd 64
#define SCALE 0.125f
#define YSEG 8

typedef __attribute__((ext_vector_type(8))) short short8;
typedef __attribute__((ext_vector_type(4))) short short4v;
typedef __attribute__((ext_vector_type(4))) float float4v;

__device__ __forceinline__ unsigned short bf16rne(float f) {
  unsigned u = __float_as_uint(f);
  u += 0x7FFFu + ((u >> 16) & 1u);
  return (unsigned short)(u >> 16);
}

__device__ __forceinline__ short8 cvt8(float4 a, float4 b) {
  short8 v;
  v[0] = (short)bf16rne(a.x); v[1] = (short)bf16rne(a.y);
  v[2] = (short)bf16rne(a.z); v[3] = (short)bf16rne(a.w);
  v[4] = (short)bf16rne(b.x); v[5] = (short)bf16rne(b.y);
  v[6] = (short)bf16rne(b.z); v[7] = (short)bf16rne(b.w);
  return v;
}

__device__ __forceinline__ short8 cvt8v(float4v a, float4v b) {
  short8 v;
  v[0] = (short)bf16rne(a[0]); v[1] = (short)bf16rne(a[1]);
  v[2] = (short)bf16rne(a[2]); v[3] = (short)bf16rne(a[3]);
  v[4] = (short)bf16rne(b[0]); v[5] = (short)bf16rne(b[1]);
  v[6] = (short)bf16rne(b[2]); v[7] = (short)bf16rne(b[3]);
  return v;
}

// ws layout (float units), Tier A (needs ~81.1 MB):
//   rb     @ 0        : 786,432 bf16 (393,216 float slots) [B][24 s][4 q][16 m=h][8 j]
//   qf     @ 393216   : [B][C] fp32
//   logits @ 442368   : [B][H][N] fp32
//   attnT  @ 885504   : [B][N][H] fp32
//   ypart  @ 1328640  : [B][YSEG][H][C] fp32 (plain stores, summed in gemm<1>)
//   cls    @ 6047232  : [B][C] fp32
//   xbf    @ 6096384  : [B][N][C] bf16 = 28,360,704 shorts = 14,180,352 slots
// Tier C (old, needs 7.87 MB): y @ 1328640 (atomic), cls @ 1918464.

// ============ k_gemm64: C(64 x 768) = A(64 x 768) @ W_rows^T + bias ===========
// MODE 0: q   = X0 @ Wq^T      (A row stride Nn*Cc;  W rows j;        out q)
// MODE 1: cls = Y_h @ Wv^T     (A = ypart[b][seg][h=jt>>2]; SEGS summed; W rows 2C+j)
// MODE 2: out0 = cls @ projW^T (A row stride Cc;     W rows j;        out row0)
template <int MODE, int SEGS>
__global__ __launch_bounds__(256) void k_gemm64(const float* __restrict__ A,
                                                const float* __restrict__ W,
                                                const float* __restrict__ bias,
                                                float* __restrict__ out) {
  int tile = blockIdx.x;            // 0..191
  int jt = tile % 48, bt = tile / 48;
  int wave = threadIdx.x >> 6, lane = threadIdx.x & 63;
  int m = lane & 15, quad = lane >> 4;
  int brow = bt * 16 + m;
  int jrow = jt * 16 + m;
  size_t aoff;
  if (MODE == 0)      aoff = (size_t)brow * (Nn * Cc);
  else if (MODE == 1) aoff = (size_t)brow * (SEGS * Hh * Cc) + (size_t)(jt >> 2) * Cc;
  else                aoff = (size_t)brow * Cc;
  size_t woff = (MODE == 1) ? (size_t)(2 * Cc + jrow) * Cc : (size_t)jrow * Cc;
  const float4v* Ap = (const float4v*)(A + aoff) + wave * 48 + quad * 2;
  const float4v* Wp = (const float4v*)(W + woff) + wave * 48 + quad * 2;
  float4v acc = {0.f, 0.f, 0.f, 0.f};
#pragma unroll
  for (int s = 0; s < 6; ++s) {
    float4v a0, a1;
    if (MODE == 1 && SEGS > 1) {
      a0 = (float4v){0.f, 0.f, 0.f, 0.f};
      a1 = a0;
#pragma unroll
      for (int seg = 0; seg < SEGS; ++seg) {
        a0 += Ap[seg * 2304 + s * 8];      // 2304 = H*C/4 float4 per seg
        a1 += Ap[seg * 2304 + s * 8 + 1];
      }
    } else {
      a0 = Ap[s * 8]; a1 = Ap[s * 8 + 1];
    }
    float4v w0 = Wp[s * 8], w1 = Wp[s * 8 + 1];
    acc = __builtin_amdgcn_mfma_f32_16x16x32_bf16(cvt8v(a0, a1), cvt8v(w0, w1),
                                                  acc, 0, 0, 0);
  }
  __shared__ float red[4][64][4];
#pragma unroll
  for (int reg = 0; reg < 4; ++reg) red[wave][lane][reg] = acc[reg];
  __syncthreads();
  if (wave == 0) {
#pragma unroll
    for (int reg = 0; reg < 4; ++reg) {
      float v = red[0][lane][reg] + red[1][lane][reg] +
                red[2][lane][reg] + red[3][lane][reg];
      int j = jt * 16 + m;
      int bb = bt * 16 + quad * 4 + reg;
      float bv = (MODE == 1) ? bias[2 * Cc + j] : bias[j];
      if (MODE == 2) out[(size_t)bb * (Nn * Cc) + j] = v + bv;
      else           out[(size_t)bb * Cc + j] = v + bv;
    }
  }
}

// ====== k_r: rb[b][s][q][h][j] = bf16(SCALE * sum_d q[b,h,d] * Wk[h,d,c]) =====
__global__ __launch_bounds__(256) void k_r(const float* __restrict__ qf,
                                           const float* __restrict__ qkv_w,
                                           unsigned short* __restrict__ rb) {
  int h = blockIdx.x % Hh, bg = blockIdx.x / Hh;
  int t = threadIdx.x;
  __shared__ float qs2[Dd][8];
  for (int idx = t; idx < 512; idx += 256) {
    int bb = idx >> 6, d = idx & 63;
    qs2[d][bb] = qf[(size_t)(bg * 8 + bb) * Cc + h * Dd + d];
  }
  __syncthreads();
  float acc[8][3];
#pragma unroll
  for (int bb = 0; bb < 8; ++bb)
#pragma unroll
    for (int i = 0; i < 3; ++i) acc[bb][i] = 0.f;
  const float* wk = qkv_w + (size_t)(Cc + h * Dd) * Cc;
  for (int d = 0; d < Dd; ++d) {
    float w0 = wk[(size_t)d * Cc + t];
    float w1 = wk[(size_t)d * Cc + t + 256];
    float w2 = wk[(size_t)d * Cc + t + 512];
    float4 qa = *(const float4*)&qs2[d][0];
    float4 qb = *(const float4*)&qs2[d][4];
    float qv[8] = {qa.x, qa.y, qa.z, qa.w, qb.x, qb.y, qb.z, qb.w};
#pragma unroll
    for (int bb = 0; bb < 8; ++bb) {
      acc[bb][0] += qv[bb] * w0;
      acc[bb][1] += qv[bb] * w1;
      acc[bb][2] += qv[bb] * w2;
    }
  }
#pragma unroll
  for (int bb = 0; bb < 8; ++bb) {
    size_t base = (size_t)(bg * 8 + bb) * 12288 + h * 8;
#pragma unroll
    for (int i = 0; i < 3; ++i) {
      int c = t + i * 256;
      int s = c >> 5, qq = (c >> 3) & 3, j = c & 7;
      rb[base + s * 512 + qq * 128 + j] = bf16rne(acc[bb][i] * SCALE);
    }
  }
}

// ===== k_prep: out[:,1:,:] = x[:,1:,:]  AND  xbf = bf16(x)  (one x stream) ====
// 6924 blocks x 256 threads; block b owns float4s [1024b, 1024b+1024).
// Thread t handles j = 1024b + t + 256k (k=0..3): every access lane-contiguous
// (16B load / 16B NT store / 8B bf16 store per lane -> full-line wave bursts).
__global__ __launch_bounds__(256) void k_prep(const float* __restrict__ x,
                                              float* __restrict__ out,
                                              unsigned short* __restrict__ xbf) {
  const float4v* xi = (const float4v*)x;
  float4v* oo = (float4v*)out;
  short4v* xb4 = (short4v*)xbf;
  int base = blockIdx.x * 1024 + threadIdx.x;
#pragma unroll
  for (int k = 0; k < 4; ++k) {
    int j = base + k * 256;                     // < 7,090,176
    float4v a = xi[j];
    short4v s;
    s[0] = (short)bf16rne(a[0]); s[1] = (short)bf16rne(a[1]);
    s[2] = (short)bf16rne(a[2]); s[3] = (short)bf16rne(a[3]);
    xb4[j] = s;
    int r = j % 110784;                         // 577*768/4 float4 per batch
    if (r >= 192)                               // skip row 0 (first 192 float4)
      __builtin_nontemporal_store(a, oo + j);
  }
}

// ===== k_logits: MFMA straight from global (no LDS, no barriers) ==============
// XBF=1: B-operand loaded pre-converted bf16 (1 x 16B load); XBF=0: fp32 + cvt.
template <int XBF>
__global__ __launch_bounds__(256) void k_logits(const float* __restrict__ x,
                                                const unsigned short* __restrict__ xbf,
                                                const unsigned short* __restrict__ rb,
                                                float* __restrict__ logits) {
  int b = blockIdx.x / 10, tile = blockIdx.x % 10;
  int wave = threadIdx.x >> 6, lane = threadIdx.x & 63;
  int m = lane & 15, quad = lane >> 4;
  int n = tile * 64 + wave * 16 + m;
  int nc = n > 576 ? 576 : n;
  const short8* ag = (const short8*)(rb + (size_t)b * 12288);
  const short8* xg8 = (const short8*)(xbf + (size_t)b * Nn * Cc) + (size_t)nc * 96 + quad;
  const float4* xg = (const float4*)(x + (size_t)b * Nn * Cc) + (size_t)nc * 192 + quad * 2;
  float4v acc = {0.f, 0.f, 0.f, 0.f};
#pragma unroll 8
  for (int s = 0; s < 24; ++s) {
    short8 a = ag[s * 64 + quad * 16 + m];
    short8 bfrag;
    if (XBF) {
      bfrag = xg8[s * 4];
    } else {
      float4 f0 = xg[s * 8], f1 = xg[s * 8 + 1];
      bfrag = cvt8(f0, f1);
    }
    acc = __builtin_amdgcn_mfma_f32_16x16x32_bf16(a, bfrag, acc, 0, 0, 0);
  }
  if (n < Nn) {
#pragma unroll
    for (int reg = 0; reg < 4; ++reg) {
      int hh = quad * 4 + reg;
      if (hh < Hh) logits[((size_t)b * Hh + hh) * Nn + n] = acc[reg];
    }
  }
}

// ---------------- softmax over n, write transposed attnT[b][n][h] -------------
__global__ __launch_bounds__(64) void k_softmax(const float* __restrict__ logits,
                                                float* __restrict__ attnT) {
  int bh = blockIdx.x;
  int b = bh / Hh, h = bh % Hh;
  const float* row = logits + (size_t)bh * Nn;
  int t = threadIdx.x;
  float vals[10];
  float m = -1e30f;
#pragma unroll
  for (int i = 0; i < 10; ++i) {
    int n = i * 64 + t;
    vals[i] = (n < Nn) ? row[n] : -1e30f;
    m = fmaxf(m, vals[i]);
  }
#pragma unroll
  for (int off = 32; off; off >>= 1) m = fmaxf(m, __shfl_down(m, off));
  m = __shfl(m, 0);
  float s = 0.f;
#pragma unroll
  for (int i = 0; i < 10; ++i) { vals[i] = __expf(vals[i] - m); s += vals[i]; }
#pragma unroll
  for (int off = 32; off; off >>= 1) s += __shfl_down(s, off);
  float inv = 1.f / __shfl(s, 0);
#pragma unroll
  for (int i = 0; i < 10; ++i) {
    int n = i * 64 + t;
    if (n < Nn) attnT[((size_t)b * Nn + n) * Hh + h] = vals[i] * inv;
  }
}

// ===== k_y3: ypart[b,seg,h,c] = sum_{n in 1/3 of seg} attn * x ================
// 512 blocks x 576 threads (9 waves). 3-way intra-block n-split, LDS reduce,
// plain stores (no atomics).
__global__ __launch_bounds__(576) void k_y3(const float* __restrict__ x,
                                            const float* __restrict__ attnT,
                                            float* __restrict__ ypart) {
  int b = blockIdx.x / YSEG, seg = blockIdx.x % YSEG;
  int c4 = threadIdx.x % 192;
  int sub = threadIdx.x / 192;              // 0..2, wave-uniform (192 = 3 waves)
  int n0 = seg * Nn / YSEG, n1 = (seg + 1) * Nn / YSEG;
  int len = n1 - n0;
  int a0 = n0 + sub * len / 3, a1 = n0 + (sub + 1) * len / 3;
  float4v acc[Hh];
#pragma unroll
  for (int h = 0; h < Hh; ++h) acc[h] = (float4v){0.f, 0.f, 0.f, 0.f};
  const float4v* x4 = (const float4v*)(x + (size_t)b * Nn * Cc);
  const float* at = attnT + (size_t)b * Nn * Hh;
#pragma unroll 4
  for (int n = a0; n < a1; ++n) {
    float4v xv = x4[(size_t)n * 192 + c4];
#pragma unroll
    for (int h = 0; h < Hh; ++h) acc[h] += at[n * Hh + h] * xv;  // at: s_load
  }
  __shared__ float4v red[192][Hh];          // 36,864 B
  if (sub == 2) {
#pragma unroll
    for (int h = 0; h < Hh; ++h) red[c4][h] = acc[h];
  }
  __syncthreads();
  if (sub == 1) {
#pragma unroll
    for (int h = 0; h < Hh; ++h) { acc[h] += red[c4][h]; red[c4][h] = acc[h]; }
  }
  __syncthreads();
  if (sub == 0) {
    float4v* yp = (float4v*)(ypart + ((size_t)(b * YSEG + seg)) * (Hh * Cc));
#pragma unroll
    for (int h = 0; h < Hh; ++h) yp[h * 192 + c4] = acc[h] + red[c4][h];
  }
}

// ----------------- Tier C fallback kernels (previous verified path) -----------
__global__ __launch_bounds__(256) void k_zero(float* __restrict__ y) {
  ((float4*)y)[blockIdx.x * 256 + threadIdx.x] = make_float4(0.f, 0.f, 0.f, 0.f);
}

__global__ __launch_bounds__(192) void k_y_atomic(const float* __restrict__ x,
                                                  const float* __restrict__ attnT,
                                                  float* __restrict__ y) {
  int b = blockIdx.x / YSEG, seg = blockIdx.x % YSEG;
  int n0 = seg * Nn / YSEG, n1 = (seg + 1) * Nn / YSEG;
  int c4 = threadIdx.x;
  float4 acc[Hh];
#pragma unroll
  for (int h = 0; h < Hh; ++h) acc[h] = make_float4(0.f, 0.f, 0.f, 0.f);
  const float4* x4 = (const float4*)(x + (size_t)b * Nn * Cc);
  const float* at = attnT + (size_t)b * Nn * Hh;
#pragma unroll 8
  for (int n = n0; n < n1; ++n) {
    float4 xv = x4[(size_t)n * 192 + c4];
#pragma unroll
    for (int h = 0; h < Hh; ++h) {
      float a = at[n * Hh + h];
      acc[h].x += a * xv.x; acc[h].y += a * xv.y;
      acc[h].z += a * xv.z; acc[h].w += a * xv.w;
    }
  }
  float* yb = y + (size_t)b * Hh * Cc;
#pragma unroll
  for (int h = 0; h < Hh; ++h) {
    float* p = yb + h * Cc + c4 * 4;
    atomicAdd(p + 0, acc[h].x); atomicAdd(p + 1, acc[h].y);
    atomicAdd(p + 2, acc[h].z); atomicAdd(p + 3, acc[h].w);
  }
}

__global__ __launch_bounds__(256) void k_copy(const float* __restrict__ x,
                                              float* __restrict__ out) {
  int idx = blockIdx.x * 256 + threadIdx.x;
  const float4* xi = (const float4*)x;
  float4* oo = (float4*)out;
  for (int i = idx; i < 7077888; i += 262144) {
    int b = i / 110592;
    int r = i - b * 110592;
    size_t off = (size_t)b * 110784 + 192 + r;
    oo[off] = xi[off];
  }
}

extern "C" void kernel_launch(void* const* d_in, const int* in_sizes, int n_in,
                              void* d_out, int out_size, void* d_ws, size_t ws_size,
                              hipStream_t stream) {
  const float* x      = (const float*)d_in[0];
  const float* qkv_w  = (const float*)d_in[1];
  const float* qkv_b  = (const float*)d_in[2];
  const float* proj_w = (const float*)d_in[3];
  const float* proj_b = (const float*)d_in[4];
  float* out = (float*)d_out;
  float* ws = (float*)d_ws;

  unsigned short* rb = (unsigned short*)ws;     // 786,432 bf16
  float* qf     = ws + 393216;
  float* logits = ws + 442368;
  float* attnT  = ws + 885504;
  float* ypart  = ws + 1328640;                 // 4,718,592 floats
  float* cls    = ws + 6047232;                 // 49,152 floats
  unsigned short* xbf = (unsigned short*)(ws + 6096384);  // 28,360,704 shorts

  const size_t NEED_XBF  = (size_t)(6096384 + 14180352) * 4;  // 81,106,944 B
  const size_t NEED_PART = (size_t)6096384 * 4;               // ~24.4 MB

  if (ws_size >= NEED_XBF) {
    // Tier A: prep (copy + bf16), bf16 logits, partial-buffer y.
    k_prep<<<6924, 256, 0, stream>>>(x, out, xbf);
    k_gemm64<0, 1><<<192, 256, 0, stream>>>(x, qkv_w, qkv_b, qf);
    k_r<<<96, 256, 0, stream>>>(qf, qkv_w, rb);
    k_logits<1><<<Bz * 10, 256, 0, stream>>>(x, xbf, rb, logits);
    k_softmax<<<Bz * Hh, 64, 0, stream>>>(logits, attnT);
    k_y3<<<Bz * YSEG, 576, 0, stream>>>(x, attnT, ypart);
    k_gemm64<1, YSEG><<<192, 256, 0, stream>>>(ypart, qkv_w, qkv_b, cls);
    k_gemm64<2, 1><<<192, 256, 0, stream>>>(cls, proj_w, proj_b, out);
  } else if (ws_size >= NEED_PART) {
    // Tier B: no xbf; fp32 logits; partial-buffer y; separate copy.
    k_gemm64<0, 1><<<192, 256, 0, stream>>>(x, qkv_w, qkv_b, qf);
    k_r<<<96, 256, 0, stream>>>(qf, qkv_w, rb);
    k_logits<0><<<Bz * 10, 256, 0, stream>>>(x, (const unsigned short*)x, rb, logits);
    k_softmax<<<Bz * Hh, 64, 0, stream>>>(logits, attnT);
    k_y3<<<Bz * YSEG, 576, 0, stream>>>(x, attnT, ypart);
    k_gemm64<1, YSEG><<<192, 256, 0, stream>>>(ypart, qkv_w, qkv_b, cls);
    k_gemm64<2, 1><<<192, 256, 0, stream>>>(cls, proj_w, proj_b, out);
    k_copy<<<1024, 256, 0, stream>>>(x, out);
  } else {
    // Tier C: previous verified pipeline (7.87 MB ws).
    float* y     = ws + 1328640;
    float* cls_c = ws + 1918464;
    k_zero<<<576, 256, 0, stream>>>(y);
    k_gemm64<0, 1><<<192, 256, 0, stream>>>(x, qkv_w, qkv_b, qf);
    k_r<<<96, 256, 0, stream>>>(qf, qkv_w, rb);
    k_logits<0><<<Bz * 10, 256, 0, stream>>>(x, (const unsigned short*)x, rb, logits);
    k_softmax<<<Bz * Hh, 64, 0, stream>>>(logits, attnT);
    k_y_atomic<<<Bz * YSEG, 192, 0, stream>>>(x, attnT, y);
    k_gemm64<1, 1><<<192, 256, 0, stream>>>(y, qkv_w, qkv_b, cls_c);
    k_gemm64<2, 1><<<192, 256, 0, stream>>>(cls_c, proj_w, proj_b, out);
  }
}

// Round 6
// 286.972 us; speedup vs baseline: 1.2761x; 1.1016x over previous
//
#include <hip/hip_runtime.h>

#define Bz 64
#define Nn 577
#define Cc 768
#define Hh 12
#define Dd 64
#define SCALE 0.125f
#define YSEG 8

typedef __attribute__((ext_vector_type(8))) short short8;
typedef __attribute__((ext_vector_type(4))) float float4v;

__device__ __forceinline__ unsigned short bf16rne(float f) {
  unsigned u = __float_as_uint(f);
  u += 0x7FFFu + ((u >> 16) & 1u);
  return (unsigned short)(u >> 16);
}

__device__ __forceinline__ short8 cvt8(float4 a, float4 b) {
  short8 v;
  v[0] = (short)bf16rne(a.x); v[1] = (short)bf16rne(a.y);
  v[2] = (short)bf16rne(a.z); v[3] = (short)bf16rne(a.w);
  v[4] = (short)bf16rne(b.x); v[5] = (short)bf16rne(b.y);
  v[6] = (short)bf16rne(b.z); v[7] = (short)bf16rne(b.w);
  return v;
}

__device__ __forceinline__ short8 cvt8v(float4v a, float4v b) {
  short8 v;
  v[0] = (short)bf16rne(a[0]); v[1] = (short)bf16rne(a[1]);
  v[2] = (short)bf16rne(a[2]); v[3] = (short)bf16rne(a[3]);
  v[4] = (short)bf16rne(b[0]); v[5] = (short)bf16rne(b[1]);
  v[6] = (short)bf16rne(b[2]); v[7] = (short)bf16rne(b[3]);
  return v;
}

// ws layout (float units), main tier (needs ~24.4 MB):
//   rb     @ 0        : 786,432 bf16 (393,216 float slots) [B][24 s][4 q][16 m=h][8 j]
//   qf     @ 393216   : [B][C] fp32
//   logits @ 442368   : [B][H][N] fp32
//   attnT  @ 885504   : [B][N][H] fp32
//   ypart  @ 1328640  : [B][YSEG][H][C] fp32 (plain stores, summed in gemm<1>)
//   cls    @ 6047232  : [B][C] fp32
// Tier C (old, needs 7.87 MB): y @ 1328640 (atomic), cls @ 1918464.

// ============ k_gemm64: C(64 x 768) = A(64 x 768) @ W_rows^T + bias ===========
// MODE 0: q   = X0 @ Wq^T      (A row stride Nn*Cc;  W rows j;        out q)
// MODE 1: cls = Y_h @ Wv^T     (A = ypart[b][seg][h=jt>>2]; SEGS summed; W rows 2C+j)
// MODE 2: out0 = cls @ projW^T (A row stride Cc;     W rows j;        out row0)
template <int MODE, int SEGS>
__global__ __launch_bounds__(256) void k_gemm64(const float* __restrict__ A,
                                                const float* __restrict__ W,
                                                const float* __restrict__ bias,
                                                float* __restrict__ out) {
  int tile = blockIdx.x;            // 0..191
  int jt = tile % 48, bt = tile / 48;
  int wave = threadIdx.x >> 6, lane = threadIdx.x & 63;
  int m = lane & 15, quad = lane >> 4;
  int brow = bt * 16 + m;
  int jrow = jt * 16 + m;
  size_t aoff;
  if (MODE == 0)      aoff = (size_t)brow * (Nn * Cc);
  else if (MODE == 1) aoff = (size_t)brow * (SEGS * Hh * Cc) + (size_t)(jt >> 2) * Cc;
  else                aoff = (size_t)brow * Cc;
  size_t woff = (MODE == 1) ? (size_t)(2 * Cc + jrow) * Cc : (size_t)jrow * Cc;
  const float4v* Ap = (const float4v*)(A + aoff) + wave * 48 + quad * 2;
  const float4v* Wp = (const float4v*)(W + woff) + wave * 48 + quad * 2;
  float4v acc = {0.f, 0.f, 0.f, 0.f};
#pragma unroll
  for (int s = 0; s < 6; ++s) {
    float4v a0, a1;
    if (MODE == 1 && SEGS > 1) {
      a0 = (float4v){0.f, 0.f, 0.f, 0.f};
      a1 = a0;
#pragma unroll
      for (int seg = 0; seg < SEGS; ++seg) {
        a0 += Ap[seg * 2304 + s * 8];      // 2304 = H*C/4 float4 per seg
        a1 += Ap[seg * 2304 + s * 8 + 1];
      }
    } else {
      a0 = Ap[s * 8]; a1 = Ap[s * 8 + 1];
    }
    float4v w0 = Wp[s * 8], w1 = Wp[s * 8 + 1];
    acc = __builtin_amdgcn_mfma_f32_16x16x32_bf16(cvt8v(a0, a1), cvt8v(w0, w1),
                                                  acc, 0, 0, 0);
  }
  __shared__ float red[4][64][4];
#pragma unroll
  for (int reg = 0; reg < 4; ++reg) red[wave][lane][reg] = acc[reg];
  __syncthreads();
  if (wave == 0) {
#pragma unroll
    for (int reg = 0; reg < 4; ++reg) {
      float v = red[0][lane][reg] + red[1][lane][reg] +
                red[2][lane][reg] + red[3][lane][reg];
      int j = jt * 16 + m;
      int bb = bt * 16 + quad * 4 + reg;
      float bv = (MODE == 1) ? bias[2 * Cc + j] : bias[j];
      if (MODE == 2) out[(size_t)bb * (Nn * Cc) + j] = v + bv;
      else           out[(size_t)bb * Cc + j] = v + bv;
    }
  }
}

// ====== k_r: rb[b][s][q][h][j] = bf16(SCALE * sum_d q[b,h,d] * Wk[h,d,c]) =====
__global__ __launch_bounds__(256) void k_r(const float* __restrict__ qf,
                                           const float* __restrict__ qkv_w,
                                           unsigned short* __restrict__ rb) {
  int h = blockIdx.x % Hh, bg = blockIdx.x / Hh;
  int t = threadIdx.x;
  __shared__ float qs2[Dd][8];
  for (int idx = t; idx < 512; idx += 256) {
    int bb = idx >> 6, d = idx & 63;
    qs2[d][bb] = qf[(size_t)(bg * 8 + bb) * Cc + h * Dd + d];
  }
  __syncthreads();
  float acc[8][3];
#pragma unroll
  for (int bb = 0; bb < 8; ++bb)
#pragma unroll
    for (int i = 0; i < 3; ++i) acc[bb][i] = 0.f;
  const float* wk = qkv_w + (size_t)(Cc + h * Dd) * Cc;
  for (int d = 0; d < Dd; ++d) {
    float w0 = wk[(size_t)d * Cc + t];
    float w1 = wk[(size_t)d * Cc + t + 256];
    float w2 = wk[(size_t)d * Cc + t + 512];
    float4 qa = *(const float4*)&qs2[d][0];
    float4 qb = *(const float4*)&qs2[d][4];
    float qv[8] = {qa.x, qa.y, qa.z, qa.w, qb.x, qb.y, qb.z, qb.w};
#pragma unroll
    for (int bb = 0; bb < 8; ++bb) {
      acc[bb][0] += qv[bb] * w0;
      acc[bb][1] += qv[bb] * w1;
      acc[bb][2] += qv[bb] * w2;
    }
  }
#pragma unroll
  for (int bb = 0; bb < 8; ++bb) {
    size_t base = (size_t)(bg * 8 + bb) * 12288 + h * 8;
#pragma unroll
    for (int i = 0; i < 3; ++i) {
      int c = t + i * 256;
      int s = c >> 5, qq = (c >> 3) & 3, j = c & 7;
      rb[base + s * 512 + qq * 128 + j] = bf16rne(acc[bb][i] * SCALE);
    }
  }
}

// ===== k_logits: MFMA straight from global (no LDS, no barriers) ==============
// fp32 x loads + inline bf16 cvt (each x row is read exactly once; x stays L3).
__global__ __launch_bounds__(256) void k_logits(const float* __restrict__ x,
                                                const unsigned short* __restrict__ rb,
                                                float* __restrict__ logits) {
  int b = blockIdx.x / 10, tile = blockIdx.x % 10;
  int wave = threadIdx.x >> 6, lane = threadIdx.x & 63;
  int m = lane & 15, quad = lane >> 4;
  int n = tile * 64 + wave * 16 + m;
  int nc = n > 576 ? 576 : n;
  const short8* ag = (const short8*)(rb + (size_t)b * 12288);
  const float4* xg = (const float4*)(x + (size_t)b * Nn * Cc) + (size_t)nc * 192 + quad * 2;
  float4v acc = {0.f, 0.f, 0.f, 0.f};
#pragma unroll 8
  for (int s = 0; s < 24; ++s) {
    short8 a = ag[s * 64 + quad * 16 + m];
    float4 f0 = xg[s * 8], f1 = xg[s * 8 + 1];
    acc = __builtin_amdgcn_mfma_f32_16x16x32_bf16(a, cvt8(f0, f1), acc, 0, 0, 0);
  }
  if (n < Nn) {
#pragma unroll
    for (int reg = 0; reg < 4; ++reg) {
      int hh = quad * 4 + reg;
      if (hh < Hh) logits[((size_t)b * Hh + hh) * Nn + n] = acc[reg];
    }
  }
}

// ---------------- softmax over n, write transposed attnT[b][n][h] -------------
__global__ __launch_bounds__(64) void k_softmax(const float* __restrict__ logits,
                                                float* __restrict__ attnT) {
  int bh = blockIdx.x;
  int b = bh / Hh, h = bh % Hh;
  const float* row = logits + (size_t)bh * Nn;
  int t = threadIdx.x;
  float vals[10];
  float m = -1e30f;
#pragma unroll
  for (int i = 0; i < 10; ++i) {
    int n = i * 64 + t;
    vals[i] = (n < Nn) ? row[n] : -1e30f;
    m = fmaxf(m, vals[i]);
  }
#pragma unroll
  for (int off = 32; off; off >>= 1) m = fmaxf(m, __shfl_down(m, off));
  m = __shfl(m, 0);
  float s = 0.f;
#pragma unroll
  for (int i = 0; i < 10; ++i) { vals[i] = __expf(vals[i] - m); s += vals[i]; }
#pragma unroll
  for (int off = 32; off; off >>= 1) s += __shfl_down(s, off);
  float inv = 1.f / __shfl(s, 0);
#pragma unroll
  for (int i = 0; i < 10; ++i) {
    int n = i * 64 + t;
    if (n < Nn) attnT[((size_t)b * Nn + n) * Hh + h] = vals[i] * inv;
  }
}

// ===== k_y3c: ypart[b,seg,h,c] = sum attn * x  AND  out[:,1:,:] = x[:,1:,:] ===
// 512 blocks x 576 threads (9 waves). Each (b,n,c4) of x is loaded by exactly
// one thread (segs partition n across blocks, subs partition n within a block,
// c4 partitions columns) -> the out-copy rides the existing read for free.
__global__ __launch_bounds__(576) void k_y3c(const float* __restrict__ x,
                                             const float* __restrict__ attnT,
                                             float* __restrict__ ypart,
                                             float* __restrict__ out) {
  int b = blockIdx.x / YSEG, seg = blockIdx.x % YSEG;
  int c4 = threadIdx.x % 192;
  int sub = threadIdx.x / 192;              // 0..2, wave-uniform (192 = 3 waves)
  int n0 = seg * Nn / YSEG, n1 = (seg + 1) * Nn / YSEG;
  int len = n1 - n0;
  int a0 = n0 + sub * len / 3, a1 = n0 + (sub + 1) * len / 3;
  float4v acc[Hh];
#pragma unroll
  for (int h = 0; h < Hh; ++h) acc[h] = (float4v){0.f, 0.f, 0.f, 0.f};
  const float4v* x4 = (const float4v*)(x + (size_t)b * Nn * Cc);
  float4v* o4 = (float4v*)(out + (size_t)b * Nn * Cc);
  const float* at = attnT + (size_t)b * Nn * Hh;
#pragma unroll 4
  for (int n = a0; n < a1; ++n) {
    float4v xv = x4[(size_t)n * 192 + c4];
    if (n)                                    // row 0 belongs to cls (gemm<2>)
      __builtin_nontemporal_store(xv, o4 + (size_t)n * 192 + c4);
#pragma unroll
    for (int h = 0; h < Hh; ++h) acc[h] += at[n * Hh + h] * xv;  // at: s_load
  }
  __shared__ float4v red[192][Hh];          // 36,864 B
  if (sub == 2) {
#pragma unroll
    for (int h = 0; h < Hh; ++h) red[c4][h] = acc[h];
  }
  __syncthreads();
  if (sub == 1) {
#pragma unroll
    for (int h = 0; h < Hh; ++h) { acc[h] += red[c4][h]; red[c4][h] = acc[h]; }
  }
  __syncthreads();
  if (sub == 0) {
    float4v* yp = (float4v*)(ypart + ((size_t)(b * YSEG + seg)) * (Hh * Cc));
#pragma unroll
    for (int h = 0; h < Hh; ++h) yp[h * 192 + c4] = acc[h] + red[c4][h];
  }
}

// ----------------- Tier C fallback kernels (previous verified path) -----------
__global__ __launch_bounds__(256) void k_zero(float* __restrict__ y) {
  ((float4*)y)[blockIdx.x * 256 + threadIdx.x] = make_float4(0.f, 0.f, 0.f, 0.f);
}

__global__ __launch_bounds__(192) void k_y_atomic(const float* __restrict__ x,
                                                  const float* __restrict__ attnT,
                                                  float* __restrict__ y) {
  int b = blockIdx.x / YSEG, seg = blockIdx.x % YSEG;
  int n0 = seg * Nn / YSEG, n1 = (seg + 1) * Nn / YSEG;
  int c4 = threadIdx.x;
  float4 acc[Hh];
#pragma unroll
  for (int h = 0; h < Hh; ++h) acc[h] = make_float4(0.f, 0.f, 0.f, 0.f);
  const float4* x4 = (const float4*)(x + (size_t)b * Nn * Cc);
  const float* at = attnT + (size_t)b * Nn * Hh;
#pragma unroll 8
  for (int n = n0; n < n1; ++n) {
    float4 xv = x4[(size_t)n * 192 + c4];
#pragma unroll
    for (int h = 0; h < Hh; ++h) {
      float a = at[n * Hh + h];
      acc[h].x += a * xv.x; acc[h].y += a * xv.y;
      acc[h].z += a * xv.z; acc[h].w += a * xv.w;
    }
  }
  float* yb = y + (size_t)b * Hh * Cc;
#pragma unroll
  for (int h = 0; h < Hh; ++h) {
    float* p = yb + h * Cc + c4 * 4;
    atomicAdd(p + 0, acc[h].x); atomicAdd(p + 1, acc[h].y);
    atomicAdd(p + 2, acc[h].z); atomicAdd(p + 3, acc[h].w);
  }
}

__global__ __launch_bounds__(256) void k_copy(const float* __restrict__ x,
                                              float* __restrict__ out) {
  int idx = blockIdx.x * 256 + threadIdx.x;
  const float4* xi = (const float4*)x;
  float4* oo = (float4*)out;
  for (int i = idx; i < 7077888; i += 262144) {
    int b = i / 110592;
    int r = i - b * 110592;
    size_t off = (size_t)b * 110784 + 192 + r;
    oo[off] = xi[off];
  }
}

extern "C" void kernel_launch(void* const* d_in, const int* in_sizes, int n_in,
                              void* d_out, int out_size, void* d_ws, size_t ws_size,
                              hipStream_t stream) {
  const float* x      = (const float*)d_in[0];
  const float* qkv_w  = (const float*)d_in[1];
  const float* qkv_b  = (const float*)d_in[2];
  const float* proj_w = (const float*)d_in[3];
  const float* proj_b = (const float*)d_in[4];
  float* out = (float*)d_out;
  float* ws = (float*)d_ws;

  unsigned short* rb = (unsigned short*)ws;     // 786,432 bf16
  float* qf     = ws + 393216;
  float* logits = ws + 442368;
  float* attnT  = ws + 885504;
  float* ypart  = ws + 1328640;                 // 4,718,592 floats
  float* cls    = ws + 6047232;                 // 49,152 floats

  const size_t NEED_PART = (size_t)6096384 * 4; // ~24.4 MB

  if (ws_size >= NEED_PART) {
    // Main: fp32 logits; attn*x with fused out-copy; partial-buffer y.
    k_gemm64<0, 1><<<192, 256, 0, stream>>>(x, qkv_w, qkv_b, qf);
    k_r<<<96, 256, 0, stream>>>(qf, qkv_w, rb);
    k_logits<<<Bz * 10, 256, 0, stream>>>(x, rb, logits);
    k_softmax<<<Bz * Hh, 64, 0, stream>>>(logits, attnT);
    k_y3c<<<Bz * YSEG, 576, 0, stream>>>(x, attnT, ypart, out);
    k_gemm64<1, YSEG><<<192, 256, 0, stream>>>(ypart, qkv_w, qkv_b, cls);
    k_gemm64<2, 1><<<192, 256, 0, stream>>>(cls, proj_w, proj_b, out);
  } else {
    // Tier C: previous verified pipeline (7.87 MB ws).
    float* y     = ws + 1328640;
    float* cls_c = ws + 1918464;
    k_zero<<<576, 256, 0, stream>>>(y);
    k_gemm64<0, 1><<<192, 256, 0, stream>>>(x, qkv_w, qkv_b, qf);
    k_r<<<96, 256, 0, stream>>>(qf, qkv_w, rb);
    k_logits<<<Bz * 10, 256, 0, stream>>>(x, rb, logits);
    k_softmax<<<Bz * Hh, 64, 0, stream>>>(logits, attnT);
    k_y_atomic<<<Bz * YSEG, 192, 0, stream>>>(x, attnT, y);
    k_gemm64<1, 1><<<192, 256, 0, stream>>>(y, qkv_w, qkv_b, cls_c);
    k_gemm64<2, 1><<<192, 256, 0, stream>>>(cls_c, proj_w, proj_b, out);
  }
}